// Round 3
// baseline (823.490 us; speedup 1.0000x reference)
//
#include <hip/hip_runtime.h>
#include <cstdio>
#include <cstdint>

typedef unsigned int u32;
typedef unsigned short u16;
typedef short bf16x8 __attribute__((ext_vector_type(8)));   // 8 bf16 = 4 VGPRs (MFMA A/B operand)
typedef float f32x4 __attribute__((ext_vector_type(4)));    // MFMA C/D operand

#define NPTS 262144
#define CDIM 256
#define KCLS 20
#define NBLK 2048          // k_gemm blocks (BM=128)
#define NSLOT 256          // BN/NLL aggregation slots
#define LSLOT 64           // loss aggregation slots

// ---- workspace layout (bytes) ----
// [0, 134217728)       : h bf16 [N][256] row-major
// + 163840             : Wt bf16 [320][256]
// + 524288             : aggBN  [256][512] f32 (sum_h[256] | sumsq_h[256] per slot)
// + 2048               : aggNLL [256][2]  f32 (nll, cnt)
// + 1024               : aggL   [64][4]   f32 (l1, cos, mask, pad)
// + 2048               : Aarr[256], Barr[256]
#define OFF_WT    ((size_t)134217728)
#define OFF_AGGBN (OFF_WT + (size_t)163840)
#define OFF_AGGNL (OFF_AGGBN + (size_t)524288)
#define OFF_AGGL  (OFF_AGGNL + (size_t)2048)
#define OFF_AB    (OFF_AGGL + (size_t)1024)
#define WS_NEED   (OFF_AB + (size_t)2048)
#define MEMSET_OFF OFF_AGGBN
#define MEMSET_LEN ((size_t)(524288 + 2048 + 1024))

__device__ __forceinline__ u16 bf16rne(float x) {
    u32 u = __float_as_uint(x);
    u32 r = u + 0x7FFFu + ((u >> 16) & 1u);   // round-to-nearest-even
    return (u16)(r >> 16);
}
__device__ __forceinline__ float bf2f(u16 b) {
    return __uint_as_float(((u32)b) << 16);
}

// ---------------------------------------------------------------------------
// kernel 0: build Wt[320][256] bf16 = transposed [w1 | ws | zero-pad]
// ---------------------------------------------------------------------------
__global__ void k_prep(const float* __restrict__ w1, const float* __restrict__ wsm,
                       u16* __restrict__ Wt) {
    int k = blockIdx.x;      // 0..255
    int n = threadIdx.x;     // 0..319
    float v = 0.f;
    if (n < 256) v = w1[k * 256 + n];
    else if (n < 256 + KCLS) v = wsm[k * KCLS + (n - 256)];
    Wt[n * 256 + k] = bf16rne(v);
}

// ---------------------------------------------------------------------------
// kernel 1: h = feat @ w1 (+b1) via bf16 MFMA; fused logits = feat @ ws (+bs)
// BM=128 rows/block, 4 waves. Wave wv: h cols [wv*64,+64) x 128 rows (acc[8][4]),
// logit rows [wv*32,+32) (lacc[2][2]).
// ---------------------------------------------------------------------------
__global__ __launch_bounds__(256, 2) void k_gemm(
    const float* __restrict__ feat, const float* __restrict__ b1,
    const float* __restrict__ bs, const int* __restrict__ segment,
    const u16* __restrict__ Wt, u16* __restrict__ h_out,
    float* __restrict__ aggBN, float* __restrict__ aggNLL)
{
    // 33792 B: K-loop uses As 8 KB + Bs 20 KB; epilogue reuses as 64x(264 u16) transpose buf
    __shared__ uint4 smem4[2112];
    uint4* const As4 = smem4;          // [4 kq][128 m] 16B slots, m XOR-swizzled by kq<<2
    uint4* const Bs4 = smem4 + 512;    // [4 kq][320 n] 16B slots

    const int t = threadIdx.x;
    const int lane = t & 63;
    const int wv = t >> 6;
    const int q = lane >> 4;          // k-quad for frag reads / row-quad of C layout
    const int i16 = lane & 15;
    const int row0 = blockIdx.x * 128;
    const int slot = blockIdx.x & (NSLOT - 1);

    const f32x4 fz = {0.f, 0.f, 0.f, 0.f};
    f32x4 acc[8][4];                  // [row-tile][col-tile]
    f32x4 lacc[2][2];                 // [logit row-tile][col-tile]
#pragma unroll
    for (int r = 0; r < 8; ++r)
#pragma unroll
        for (int c = 0; c < 4; ++c) acc[r][c] = fz;
    lacc[0][0] = fz; lacc[0][1] = fz; lacc[1][0] = fz; lacc[1][1] = fz;

    // feat staging: thread t -> rows sm and sm+64, k-group sq (8 fp32 each)
    const int sm = t >> 2;            // 0..63
    const int sq = t & 3;
    const float* fsrcA = feat + (size_t)(row0 + sm) * 256 + sq * 8;
    const float* fsrcB = feat + (size_t)(row0 + 64 + sm) * 256 + sq * 8;
    const int As_wslotA = sq * 128 + (sm ^ (sq << 2));
    const int As_wslotB = sq * 128 + ((sm + 64) ^ (sq << 2));

    float4 f0 = *(const float4*)(fsrcA);
    float4 f1 = *(const float4*)(fsrcA + 4);
    float4 g0 = *(const float4*)(fsrcB);
    float4 g1 = *(const float4*)(fsrcB + 4);

#pragma unroll 1
    for (int kc = 0; kc < 8; ++kc) {
        const int k0 = kc * 32;
        // ---- stage feat tile (fp32 -> bf16, two ds_write_b128) ----
        {
            uint4 pk;
            pk.x = (u32)bf16rne(f0.x) | ((u32)bf16rne(f0.y) << 16);
            pk.y = (u32)bf16rne(f0.z) | ((u32)bf16rne(f0.w) << 16);
            pk.z = (u32)bf16rne(f1.x) | ((u32)bf16rne(f1.y) << 16);
            pk.w = (u32)bf16rne(f1.z) | ((u32)bf16rne(f1.w) << 16);
            As4[As_wslotA] = pk;
            pk.x = (u32)bf16rne(g0.x) | ((u32)bf16rne(g0.y) << 16);
            pk.y = (u32)bf16rne(g0.z) | ((u32)bf16rne(g0.w) << 16);
            pk.z = (u32)bf16rne(g1.x) | ((u32)bf16rne(g1.y) << 16);
            pk.w = (u32)bf16rne(g1.z) | ((u32)bf16rne(g1.w) << 16);
            As4[As_wslotB] = pk;
        }
        // ---- stage Wt slab via global_load_lds width=16 (wave wv handles k-quad wv) ----
#pragma unroll
        for (int i = 0; i < 5; ++i) {
            const u16* src = Wt + (size_t)(i * 64 + lane) * 256 + k0 + wv * 8;
            u32* dst = (u32*)&Bs4[wv * 320 + i * 64];   // dest = base + lane*16
            __builtin_amdgcn_global_load_lds(
                (const __attribute__((address_space(1))) u32*)src,
                (__attribute__((address_space(3))) u32*)dst, 16, 0, 0);
        }
        __syncthreads();

        // prefetch next feat chunk under the MFMAs
        float4 fn0, fn1, gn0, gn1;
        if (kc < 7) {
            fn0 = *(const float4*)(fsrcA + (kc + 1) * 32);
            fn1 = *(const float4*)(fsrcA + (kc + 1) * 32 + 4);
            gn0 = *(const float4*)(fsrcB + (kc + 1) * 32);
            gn1 = *(const float4*)(fsrcB + (kc + 1) * 32 + 4);
        }

        // ---- fragments + MFMA ----
        bf16x8 bfr[4], lbf[2];
#pragma unroll
        for (int c = 0; c < 4; ++c)
            bfr[c] = *(const bf16x8*)&Bs4[q * 320 + wv * 64 + c * 16 + i16];
#pragma unroll
        for (int x = 0; x < 2; ++x)
            lbf[x] = *(const bf16x8*)&Bs4[q * 320 + 256 + x * 16 + i16];

#pragma unroll
        for (int r = 0; r < 8; ++r) {
            bf16x8 af = *(const bf16x8*)&As4[q * 128 + ((r * 16 + i16) ^ (q << 2))];
#pragma unroll
            for (int c = 0; c < 4; ++c)
                acc[r][c] = __builtin_amdgcn_mfma_f32_16x16x32_bf16(af, bfr[c], acc[r][c], 0, 0, 0);
        }
#pragma unroll
        for (int lt = 0; lt < 2; ++lt) {
            bf16x8 la = *(const bf16x8*)&As4[q * 128 + ((wv * 32 + lt * 16 + i16) ^ (q << 2))];
#pragma unroll
            for (int x = 0; x < 2; ++x)
                lacc[lt][x] = __builtin_amdgcn_mfma_f32_16x16x32_bf16(la, lbf[x], lacc[lt][x], 0, 0, 0);
        }
        __syncthreads();
        f0 = fn0; f1 = fn1; g0 = gn0; g1 = gn1;
    }

    // ---- epilogue ----
    float b1v[4];
#pragma unroll
    for (int c = 0; c < 4; ++c) b1v[c] = b1[wv * 64 + c * 16 + i16];
    float bsv0 = bs[i16];
    float bsv1 = (16 + i16 < KCLS) ? bs[16 + i16] : 0.f;

    // seg-head NLL for this wave's 32 logit rows. C layout: col=i16, row=q*4+j.
    float nllacc = 0.f, cntacc = 0.f;
#pragma unroll
    for (int lt = 0; lt < 2; ++lt)
#pragma unroll
    for (int j = 0; j < 4; ++j) {
        int rowr = row0 + wv * 32 + lt * 16 + q * 4 + j;
        float l0 = lacc[lt][0][j] + bsv0;                   // cols 0..15
        float l1raw = lacc[lt][1][j] + bsv1;                // cols 16..31 (only 16..19 real)
        float l1m = (i16 < 4) ? l1raw : -3.0e38f;
        float mx = fmaxf(l0, l1m);
#pragma unroll
        for (int d = 1; d < 16; d <<= 1) mx = fmaxf(mx, __shfl_xor(mx, d));
        float s = __expf(l0 - mx) + ((i16 < 4) ? __expf(l1raw - mx) : 0.f);
#pragma unroll
        for (int d = 1; d < 16; d <<= 1) s += __shfl_xor(s, d);
        int tg = segment[rowr];
        float v0 = __shfl(l0, (lane & 48) + (tg & 15));
        float v1 = __shfl(l1raw, (lane & 48) + ((tg - 16) & 15));
        float lt_ = (tg < 16) ? v0 : v1;
        if (i16 == 0 && tg >= 0) {                          // ignore_index = -1
            nllacc += __logf(s) + mx - lt_;
            cntacc += 1.f;
        }
    }
#pragma unroll
    for (int d = 1; d < 64; d <<= 1) {
        nllacc += __shfl_xor(nllacc, d);
        cntacc += __shfl_xor(cntacc, d);
    }
    if (lane == 0) {
        atomicAdd(aggNLL + slot * 2 + 0, nllacc);
        atomicAdd(aggNLL + slot * 2 + 1, cntacc);
    }

    // per-channel sum / sumsq over this block's 128 rows -> 256-slot fan-out
#pragma unroll
    for (int c = 0; c < 4; ++c) {
        float s1 = 0.f, s2 = 0.f;
#pragma unroll
        for (int r = 0; r < 8; ++r)
#pragma unroll
            for (int j = 0; j < 4; ++j) {
                float v = acc[r][c][j] + b1v[c];
                s1 += v; s2 = fmaf(v, v, s2);
            }
        s1 += __shfl_xor(s1, 16); s1 += __shfl_xor(s1, 32);
        s2 += __shfl_xor(s2, 16); s2 += __shfl_xor(s2, 32);
        if (q == 0) {
            int ch = wv * 64 + c * 16 + i16;
            atomicAdd(aggBN + slot * 512 + ch, s1);
            atomicAdd(aggBN + slot * 512 + 256 + ch, s2);
        }
    }

    // transpose h to row-major via LDS, two 64-row passes (rows padded to 264 u16)
    u16* Ht = (u16*)smem4;
#pragma unroll 1
    for (int p = 0; p < 2; ++p) {
#pragma unroll
        for (int r = p * 4; r < p * 4 + 4; ++r)
#pragma unroll
            for (int c = 0; c < 4; ++c)
#pragma unroll
                for (int j = 0; j < 4; ++j) {
                    float v = acc[r][c][j] + b1v[c];
                    int rw = (r - p * 4) * 16 + q * 4 + j;
                    int cl = wv * 64 + c * 16 + i16;
                    Ht[rw * 264 + cl] = bf16rne(v);
                }
        __syncthreads();
        // coalesced store: 64 rows x 512 B
#pragma unroll
        for (int i = 0; i < 8; ++i) {
            int chunk = i * 256 + t;          // 0..2047 of 16B
            int m = chunk >> 5;
            int off = (chunk & 31) * 16;
            uint4 v = *(const uint4*)((const char*)smem4 + m * 528 + off);
            *(uint4*)((char*)h_out + (size_t)(row0 + p * 64 + m) * 512 + off) = v;
        }
        __syncthreads();
    }
}

// ---------------------------------------------------------------------------
// kernel 2: reduce BN slot partials -> affine hn = h*A + B  (256 blocks x 64)
// ---------------------------------------------------------------------------
__global__ void k_reduce(const float* __restrict__ gamma, const float* __restrict__ beta,
                         const float* __restrict__ aggBN,
                         float* __restrict__ Aarr, float* __restrict__ Barr) {
    int c = blockIdx.x;      // channel
    int l = threadIdx.x;     // 0..63
    float s1 = 0.f, s2 = 0.f;
#pragma unroll
    for (int i = 0; i < 4; ++i) {
        int s = l + i * 64;
        s1 += aggBN[s * 512 + c];
        s2 += aggBN[s * 512 + 256 + c];
    }
#pragma unroll
    for (int d = 1; d < 64; d <<= 1) {
        s1 += __shfl_xor(s1, d);
        s2 += __shfl_xor(s2, d);
    }
    if (l == 0) {
        const float inv = 1.f / (float)NPTS;
        float mu = s1 * inv;
        float var = fmaxf(s2 * inv - mu * mu, 0.f);   // biased var (torch BN)
        float a = gamma[c] * rsqrtf(var + 1e-3f);
        Aarr[c] = a;
        Barr[c] = beta[c] - mu * a;
    }
}

// ---------------------------------------------------------------------------
// kernel 3: bias_pred = relu(h*A+B) @ w2 + b2 via MFMA, masked L1 + cosine.
// 16 rows per mfma-group: A-frag = affine+relu'd h (lane: m=i16, k=q*8+j),
// B-frag = w2 cols (n=i16, only n<3 nonzero), built once.
// C layout: col=i16, row=q*4+j -> xyz gathered through per-wave LDS strip.
// ---------------------------------------------------------------------------
__global__ __launch_bounds__(256) void k_loss(
    const u16* __restrict__ h, const float* __restrict__ Aarr, const float* __restrict__ Barr,
    const float* __restrict__ w2, const float* __restrict__ b2,
    const float* __restrict__ coord, const float* __restrict__ cent,
    const int* __restrict__ inst, float* __restrict__ aggL)
{
    __shared__ float w2s[768];
    __shared__ float As_l[256], Bs_l[256];
    __shared__ float bp[4][16][4];    // per wave: 16 rows x {x,y,z,pad}
    __shared__ float red[12];

    const int t = threadIdx.x;
    const int lane = t & 63;
    const int wv = t >> 6;
    const int q = lane >> 4;
    const int i16 = lane & 15;

    if (t < 256) { As_l[t] = Aarr[t]; Bs_l[t] = Barr[t]; }
    for (int i = t; i < 768; i += 256) w2s[i] = w2[i];
    __syncthreads();

    // build w2 B-frags for all 8 k-chunks (held in regs, reused every group)
    bf16x8 wfr[8];
#pragma unroll
    for (int kc = 0; kc < 8; ++kc) {
        bf16x8 f;
#pragma unroll
        for (int j = 0; j < 8; ++j) {
            int k = kc * 32 + q * 8 + j;
            float v = (i16 < 3) ? w2s[k * 3 + i16] : 0.f;
            ((u16*)&f)[j] = bf16rne(v);
        }
        wfr[kc] = f;
    }
    float b2x = b2[0], b2y = b2[1], b2z = b2[2];

    const f32x4 fz = {0.f, 0.f, 0.f, 0.f};
    float l1a = 0.f, cosa = 0.f, ma = 0.f;

    // 1024 blocks * 4 waves * 4 groups * 16 rows = 262144
    const int wavebase = blockIdx.x * 256 + wv * 64;
#pragma unroll 1
    for (int g = 0; g < 4; ++g) {
        const int rb = wavebase + g * 16;
        f32x4 c = fz;
#pragma unroll
        for (int kc = 0; kc < 8; ++kc) {
            bf16x8 hf = *(const bf16x8*)(h + (size_t)(rb + i16) * 256 + kc * 32 + q * 8);
            float4 a0 = *(const float4*)(As_l + kc * 32 + q * 8);
            float4 a1 = *(const float4*)(As_l + kc * 32 + q * 8 + 4);
            float4 b0 = *(const float4*)(Bs_l + kc * 32 + q * 8);
            float4 b1 = *(const float4*)(Bs_l + kc * 32 + q * 8 + 4);
            float av[8] = {a0.x, a0.y, a0.z, a0.w, a1.x, a1.y, a1.z, a1.w};
            float bv[8] = {b0.x, b0.y, b0.z, b0.w, b1.x, b1.y, b1.z, b1.w};
            bf16x8 hn;
#pragma unroll
            for (int j = 0; j < 8; ++j) {
                float x = fmaxf(fmaf(bf2f(((const u16*)&hf)[j]), av[j], bv[j]), 0.f);
                ((u16*)&hn)[j] = bf16rne(x);
            }
            c = __builtin_amdgcn_mfma_f32_16x16x32_bf16(hn, wfr[kc], c, 0, 0, 0);
        }
        // scatter xyz to per-wave LDS strip (wave-internal: DS ops are wave-ordered)
        if (i16 < 3) {
#pragma unroll
            for (int j = 0; j < 4; ++j) bp[wv][q * 4 + j][i16] = c[j];
        }
        if (lane < 16) {
            int row = rb + lane;
            float4 P = *(const float4*)bp[wv][lane];
            float bpx = P.x + b2x, bpy = P.y + b2y, bpz = P.z + b2z;
            const float* cp = coord + (size_t)row * 3;
            const float* ip = cent + (size_t)row * 3;
            float gx = ip[0] - cp[0], gy = ip[1] - cp[1], gz = ip[2] - cp[2];
            float mk = (inst[row] != -1) ? 1.f : 0.f;
            float l1 = fabsf(bpx - gx) + fabsf(bpy - gy) + fabsf(bpz - gz);
            float np = sqrtf(fmaf(bpx, bpx, fmaf(bpy, bpy, bpz * bpz)));
            float ng = sqrtf(fmaf(gx, gx, fmaf(gy, gy, gz * gz)));
            float dp = fmaf(bpx, gx, fmaf(bpy, gy, bpz * gz));
            float cosv = -dp / ((np + 1e-8f) * (ng + 1e-8f));
            l1a = fmaf(l1, mk, l1a);
            cosa = fmaf(cosv, mk, cosa);
            ma += mk;
        }
    }
#pragma unroll
    for (int d = 1; d < 64; d <<= 1) {
        l1a += __shfl_xor(l1a, d);
        cosa += __shfl_xor(cosa, d);
        ma += __shfl_xor(ma, d);
    }
    if (lane == 0) { red[wv] = l1a; red[4 + wv] = cosa; red[8 + wv] = ma; }
    __syncthreads();
    if (t == 0) {
        int slot = blockIdx.x & (LSLOT - 1);
        atomicAdd(aggL + slot * 4 + 0, red[0] + red[1] + red[2] + red[3]);
        atomicAdd(aggL + slot * 4 + 1, red[4] + red[5] + red[6] + red[7]);
        atomicAdd(aggL + slot * 4 + 2, red[8] + red[9] + red[10] + red[11]);
    }
}

// ---------------------------------------------------------------------------
// kernel 4: final scalars — reduce NLL + loss slots, emit 4 outputs (1 wave)
// ---------------------------------------------------------------------------
__global__ void k_final(const float* __restrict__ aggNLL, const float* __restrict__ aggL,
                        float* __restrict__ out) {
    int lane = threadIdx.x;   // 0..63
    float nll = 0.f, cnt = 0.f;
#pragma unroll
    for (int i = 0; i < 4; ++i) {
        int s = lane + i * 64;
        nll += aggNLL[s * 2 + 0];
        cnt += aggNLL[s * 2 + 1];
    }
    float l1 = aggL[lane * 4 + 0];
    float cs = aggL[lane * 4 + 1];
    float mk = aggL[lane * 4 + 2];
#pragma unroll
    for (int d = 1; d < 64; d <<= 1) {
        nll += __shfl_xor(nll, d);
        cnt += __shfl_xor(cnt, d);
        l1 += __shfl_xor(l1, d);
        cs += __shfl_xor(cs, d);
        mk += __shfl_xor(mk, d);
    }
    if (lane == 0) {
        float seg = nll / (cnt + 1e-8f);
        float l1l = l1 / (mk + 1e-8f);
        float csl = cs / (mk + 1e-8f);
        out[0] = seg + l1l + csl;
        out[1] = seg;
        out[2] = l1l;
        out[3] = csl;
    }
}

extern "C" void kernel_launch(void* const* d_in, const int* in_sizes, int n_in,
                              void* d_out, int out_size, void* d_ws, size_t ws_size,
                              hipStream_t stream) {
    const float* feat   = (const float*)d_in[0];
    const float* coord  = (const float*)d_in[1];
    const float* cent   = (const float*)d_in[2];
    const int* segment  = (const int*)d_in[3];
    const int* inst     = (const int*)d_in[4];
    const float* w1     = (const float*)d_in[5];
    const float* b1     = (const float*)d_in[6];
    const float* gamma  = (const float*)d_in[7];
    const float* beta   = (const float*)d_in[8];
    const float* w2     = (const float*)d_in[9];
    const float* b2     = (const float*)d_in[10];
    const float* wsm    = (const float*)d_in[11];
    const float* bs     = (const float*)d_in[12];
    float* out = (float*)d_out;

    char* wsb = (char*)d_ws;
    u16* h_ws    = (u16*)wsb;
    u16* Wt      = (u16*)(wsb + OFF_WT);
    float* aggBN = (float*)(wsb + OFF_AGGBN);
    float* aggNL = (float*)(wsb + OFF_AGGNL);
    float* aggL  = (float*)(wsb + OFF_AGGL);
    float* Aarr  = (float*)(wsb + OFF_AB);
    float* Barr  = Aarr + 256;

    if (ws_size < WS_NEED)
        fprintf(stderr, "kernel_launch: ws_size=%zu < needed %zu — WILL CORRUPT\n",
                ws_size, (size_t)WS_NEED);

    hipMemsetAsync(wsb + MEMSET_OFF, 0, MEMSET_LEN, stream);
    k_prep<<<256, 320, 0, stream>>>(w1, wsm, Wt);
    k_gemm<<<NBLK, 256, 0, stream>>>(feat, b1, bs, segment, Wt, h_ws, aggBN, aggNL);
    k_reduce<<<256, 64, 0, stream>>>(gamma, beta, aggBN, Aarr, Barr);
    k_loss<<<1024, 256, 0, stream>>>(h_ws, Aarr, Barr, w2, b2, coord, cent, inst, aggL);
    k_final<<<1, 64, 0, stream>>>(aggNL, aggL, out);
}

// Round 4
// 719.233 us; speedup vs baseline: 1.1450x; 1.1450x over previous
//
#include <hip/hip_runtime.h>
#include <cstdio>
#include <cstdint>

typedef unsigned int u32;
typedef unsigned short u16;
typedef short bf16x8 __attribute__((ext_vector_type(8)));   // 8 bf16 = 4 VGPRs (MFMA A/B operand)
typedef float f32x4 __attribute__((ext_vector_type(4)));    // MFMA C/D operand

#define NPTS 262144
#define CDIM 256
#define KCLS 20
#define NBLK 4096          // k_gemm blocks (BM=64)
#define NSLOT 256          // BN/NLL aggregation slots
#define LSLOT 64           // loss aggregation slots

// ---- workspace layout (bytes) ----
// [0, 134217728)       : h bf16 [N][256] row-major
// + 163840             : Wt bf16 [320][256]
// + 524288             : aggBN  [256][512] f32 (sum_h[256] | sumsq_h[256] per slot)
// + 2048               : aggNLL [256][2]  f32 (nll, cnt)
// + 1024               : aggL   [64][4]   f32 (l1, cos, mask, pad)
// + 2048               : Aarr[256], Barr[256]
#define OFF_WT    ((size_t)134217728)
#define OFF_AGGBN (OFF_WT + (size_t)163840)
#define OFF_AGGNL (OFF_AGGBN + (size_t)524288)
#define OFF_AGGL  (OFF_AGGNL + (size_t)2048)
#define OFF_AB    (OFF_AGGL + (size_t)1024)
#define WS_NEED   (OFF_AB + (size_t)2048)
#define MEMSET_OFF OFF_AGGBN
#define MEMSET_LEN ((size_t)(524288 + 2048 + 1024))

__device__ __forceinline__ u16 bf16rne(float x) {
    u32 u = __float_as_uint(x);
    u32 r = u + 0x7FFFu + ((u >> 16) & 1u);   // round-to-nearest-even
    return (u16)(r >> 16);
}
__device__ __forceinline__ float bf2f(u16 b) {
    return __uint_as_float(((u32)b) << 16);
}

// ---------------------------------------------------------------------------
// kernel 0: build Wt[320][256] bf16 = transposed [w1 | ws | zero-pad]
// ---------------------------------------------------------------------------
__global__ void k_prep(const float* __restrict__ w1, const float* __restrict__ wsm,
                       u16* __restrict__ Wt) {
    int k = blockIdx.x;      // 0..255
    int n = threadIdx.x;     // 0..319
    float v = 0.f;
    if (n < 256) v = w1[k * 256 + n];
    else if (n < 256 + KCLS) v = wsm[k * KCLS + (n - 256)];
    Wt[n * 256 + k] = bf16rne(v);
}

// ---------------------------------------------------------------------------
// kernel 1: h = feat @ w1 (+b1) via bf16 MFMA; fused logits = feat @ ws (+bs)
// BARRIER-FREE K-loop: no LDS staging at all.
//  A-frag: lane(q,i16) loads feat[row0+r*16+i16][k0+q*8 ..+8] (2x dwordx4 fp32)
//          and packs to bf16 — exactly the 16x16x32 A layout (m=i16, k=q*8+j).
//  B-frag: lane(q,i16) loads Wt[col][k0+q*8 ..+8] (1x dwordx4 bf16) — exactly
//          the B layout (n=i16, k=q*8+j). Wt is 160 KB -> L2-resident.
// Waves are fully independent until the epilogue; compiler emits fine-grained
// vmcnt waits instead of a barrier drain.
// ---------------------------------------------------------------------------
__global__ __launch_bounds__(256) void k_gemm(
    const float* __restrict__ feat, const float* __restrict__ b1,
    const float* __restrict__ bs, const int* __restrict__ segment,
    const u16* __restrict__ Wt, u16* __restrict__ h_out,
    float* __restrict__ aggBN, float* __restrict__ aggNLL)
{
    // LDS only for the epilogue transpose: 64 rows x 264 u16 = 33792 B
    __shared__ uint4 smem4[2112];

    const int t = threadIdx.x;
    const int lane = t & 63;
    const int wv = t >> 6;
    const int q = lane >> 4;          // k-quad / row-quad of C layout
    const int i16 = lane & 15;
    const int row0 = blockIdx.x * 64;
    const int slot = blockIdx.x & (NSLOT - 1);

    const f32x4 fz = {0.f, 0.f, 0.f, 0.f};
    f32x4 acc[4][4];                  // [row-tile][col-tile]
    f32x4 lacc[2];                    // logit col-tiles (cols 256+{0,16})
#pragma unroll
    for (int r = 0; r < 4; ++r)
#pragma unroll
        for (int c = 0; c < 4; ++c) acc[r][c] = fz;
    lacc[0] = fz; lacc[1] = fz;

    // per-lane base pointers
    const float* fbase = feat + (size_t)(row0 + i16) * 256 + q * 8;   // + r*16*256 + kc*32
    const u16* wbase = Wt + (size_t)i16 * 256 + q * 8;                 // + col*256 + kc*32

#pragma unroll 1
    for (int kc = 0; kc < 8; ++kc) {
        const int k0 = kc * 32;
        // ---- B fragments: direct 16B bf16 loads from L2-resident Wt ----
        bf16x8 bfr[4], lbf[2];
#pragma unroll
        for (int c = 0; c < 4; ++c)
            bfr[c] = *(const bf16x8*)(wbase + (size_t)(wv * 64 + c * 16) * 256 + k0);
#pragma unroll
        for (int x = 0; x < 2; ++x)
            lbf[x] = *(const bf16x8*)(wbase + (size_t)(256 + x * 16) * 256 + k0);

        // ---- A fragments: direct fp32 loads + pack to bf16 ----
        float4 x0[4], x1[4];
#pragma unroll
        for (int r = 0; r < 4; ++r) {
            const float* p = fbase + (size_t)(r * 16) * 256 + k0;
            x0[r] = *(const float4*)(p);
            x1[r] = *(const float4*)(p + 4);
        }
        bf16x8 af[4];
#pragma unroll
        for (int r = 0; r < 4; ++r) {
            bf16x8 f;
            ((u32*)&f)[0] = (u32)bf16rne(x0[r].x) | ((u32)bf16rne(x0[r].y) << 16);
            ((u32*)&f)[1] = (u32)bf16rne(x0[r].z) | ((u32)bf16rne(x0[r].w) << 16);
            ((u32*)&f)[2] = (u32)bf16rne(x1[r].x) | ((u32)bf16rne(x1[r].y) << 16);
            ((u32*)&f)[3] = (u32)bf16rne(x1[r].z) | ((u32)bf16rne(x1[r].w) << 16);
            af[r] = f;
        }

        // ---- MFMAs ----
#pragma unroll
        for (int r = 0; r < 4; ++r)
#pragma unroll
            for (int c = 0; c < 4; ++c)
                acc[r][c] = __builtin_amdgcn_mfma_f32_16x16x32_bf16(af[r], bfr[c], acc[r][c], 0, 0, 0);
#pragma unroll
        for (int x = 0; x < 2; ++x)
            lacc[x] = __builtin_amdgcn_mfma_f32_16x16x32_bf16(af[wv], lbf[x], lacc[x], 0, 0, 0);
    }

    // ---- epilogue (identical to the validated R2 version) ----
    float b1v[4];
#pragma unroll
    for (int c = 0; c < 4; ++c) b1v[c] = b1[wv * 64 + c * 16 + i16];
    float bsv0 = bs[i16];
    float bsv1 = (16 + i16 < KCLS) ? bs[16 + i16] : 0.f;

    // seg-head NLL for this wave's 16 logit rows. C layout: col=i16, row=q*4+j.
    float nllacc = 0.f, cntacc = 0.f;
#pragma unroll
    for (int j = 0; j < 4; ++j) {
        int rowr = row0 + wv * 16 + q * 4 + j;
        float l0 = lacc[0][j] + bsv0;                       // cols 0..15
        float l1raw = lacc[1][j] + bsv1;                    // cols 16..31 (only 16..19 real)
        float l1m = (i16 < 4) ? l1raw : -3.0e38f;
        float mx = fmaxf(l0, l1m);
#pragma unroll
        for (int d = 1; d < 16; d <<= 1) mx = fmaxf(mx, __shfl_xor(mx, d));
        float s = __expf(l0 - mx) + ((i16 < 4) ? __expf(l1raw - mx) : 0.f);
#pragma unroll
        for (int d = 1; d < 16; d <<= 1) s += __shfl_xor(s, d);
        int tg = segment[rowr];
        float v0 = __shfl(l0, (lane & 48) + (tg & 15));
        float v1 = __shfl(l1raw, (lane & 48) + ((tg - 16) & 15));
        float lt = (tg < 16) ? v0 : v1;
        if (i16 == 0 && tg >= 0) {                          // ignore_index = -1
            nllacc += __logf(s) + mx - lt;
            cntacc += 1.f;
        }
    }
#pragma unroll
    for (int d = 1; d < 64; d <<= 1) {
        nllacc += __shfl_xor(nllacc, d);
        cntacc += __shfl_xor(cntacc, d);
    }
    if (lane == 0) {
        atomicAdd(aggNLL + slot * 2 + 0, nllacc);
        atomicAdd(aggNLL + slot * 2 + 1, cntacc);
    }

    // per-channel sum / sumsq over this block's 64 rows -> 256-slot fan-out
#pragma unroll
    for (int c = 0; c < 4; ++c) {
        float s1 = 0.f, s2 = 0.f;
#pragma unroll
        for (int r = 0; r < 4; ++r)
#pragma unroll
            for (int j = 0; j < 4; ++j) {
                float v = acc[r][c][j] + b1v[c];
                s1 += v; s2 = fmaf(v, v, s2);
            }
        s1 += __shfl_xor(s1, 16); s1 += __shfl_xor(s1, 32);
        s2 += __shfl_xor(s2, 16); s2 += __shfl_xor(s2, 32);
        if (q == 0) {
            int ch = wv * 64 + c * 16 + i16;
            atomicAdd(aggBN + slot * 512 + ch, s1);
            atomicAdd(aggBN + slot * 512 + 256 + ch, s2);
        }
    }

    // transpose h to row-major via LDS (rows padded to 264 u16 = 528 B)
    u16* Ht = (u16*)smem4;
#pragma unroll
    for (int r = 0; r < 4; ++r)
#pragma unroll
        for (int c = 0; c < 4; ++c)
#pragma unroll
            for (int j = 0; j < 4; ++j) {
                float v = acc[r][c][j] + b1v[c];
                int rw = r * 16 + q * 4 + j;
                int cl = wv * 64 + c * 16 + i16;
                Ht[rw * 264 + cl] = bf16rne(v);
            }
    __syncthreads();
    // coalesced store: 64 rows x 512 B
#pragma unroll
    for (int i = 0; i < 8; ++i) {
        int chunk = i * 256 + t;          // 0..2047 of 16B
        int m = chunk >> 5;
        int off = (chunk & 31) * 16;
        uint4 v = *(const uint4*)((const char*)smem4 + m * 528 + off);
        *(uint4*)((char*)h_out + (size_t)(row0 + m) * 512 + off) = v;
    }
}

// ---------------------------------------------------------------------------
// kernel 2: reduce BN slot partials -> affine hn = h*A + B  (256 blocks x 64)
// ---------------------------------------------------------------------------
__global__ void k_reduce(const float* __restrict__ gamma, const float* __restrict__ beta,
                         const float* __restrict__ aggBN,
                         float* __restrict__ Aarr, float* __restrict__ Barr) {
    int c = blockIdx.x;      // channel
    int l = threadIdx.x;     // 0..63
    float s1 = 0.f, s2 = 0.f;
#pragma unroll
    for (int i = 0; i < 4; ++i) {
        int s = l + i * 64;
        s1 += aggBN[s * 512 + c];
        s2 += aggBN[s * 512 + 256 + c];
    }
#pragma unroll
    for (int d = 1; d < 64; d <<= 1) {
        s1 += __shfl_xor(s1, d);
        s2 += __shfl_xor(s2, d);
    }
    if (l == 0) {
        const float inv = 1.f / (float)NPTS;
        float mu = s1 * inv;
        float var = fmaxf(s2 * inv - mu * mu, 0.f);   // biased var (torch BN)
        float a = gamma[c] * rsqrtf(var + 1e-3f);
        Aarr[c] = a;
        Barr[c] = beta[c] - mu * a;
    }
}

// ---------------------------------------------------------------------------
// kernel 3: bias_pred = relu(h*A+B) @ w2 + b2 via MFMA, masked L1 + cosine.
// ---------------------------------------------------------------------------
__global__ __launch_bounds__(256) void k_loss(
    const u16* __restrict__ h, const float* __restrict__ Aarr, const float* __restrict__ Barr,
    const float* __restrict__ w2, const float* __restrict__ b2,
    const float* __restrict__ coord, const float* __restrict__ cent,
    const int* __restrict__ inst, float* __restrict__ aggL)
{
    __shared__ float w2s[768];
    __shared__ float As_l[256], Bs_l[256];
    __shared__ float bp[4][16][4];    // per wave: 16 rows x {x,y,z,pad}
    __shared__ float red[12];

    const int t = threadIdx.x;
    const int lane = t & 63;
    const int wv = t >> 6;
    const int q = lane >> 4;
    const int i16 = lane & 15;

    if (t < 256) { As_l[t] = Aarr[t]; Bs_l[t] = Barr[t]; }
    for (int i = t; i < 768; i += 256) w2s[i] = w2[i];
    __syncthreads();

    // build w2 B-frags for all 8 k-chunks (held in regs, reused every group)
    bf16x8 wfr[8];
#pragma unroll
    for (int kc = 0; kc < 8; ++kc) {
        bf16x8 f;
#pragma unroll
        for (int j = 0; j < 8; ++j) {
            int k = kc * 32 + q * 8 + j;
            float v = (i16 < 3) ? w2s[k * 3 + i16] : 0.f;
            ((u16*)&f)[j] = bf16rne(v);
        }
        wfr[kc] = f;
    }
    float b2x = b2[0], b2y = b2[1], b2z = b2[2];

    const f32x4 fz = {0.f, 0.f, 0.f, 0.f};
    float l1a = 0.f, cosa = 0.f, ma = 0.f;

    // 1024 blocks * 4 waves * 4 groups * 16 rows = 262144
    const int wavebase = blockIdx.x * 256 + wv * 64;
#pragma unroll 1
    for (int g = 0; g < 4; ++g) {
        const int rb = wavebase + g * 16;
        f32x4 c = fz;
#pragma unroll
        for (int kc = 0; kc < 8; ++kc) {
            bf16x8 hf = *(const bf16x8*)(h + (size_t)(rb + i16) * 256 + kc * 32 + q * 8);
            float4 a0 = *(const float4*)(As_l + kc * 32 + q * 8);
            float4 a1 = *(const float4*)(As_l + kc * 32 + q * 8 + 4);
            float4 b0 = *(const float4*)(Bs_l + kc * 32 + q * 8);
            float4 b1 = *(const float4*)(Bs_l + kc * 32 + q * 8 + 4);
            float av[8] = {a0.x, a0.y, a0.z, a0.w, a1.x, a1.y, a1.z, a1.w};
            float bv[8] = {b0.x, b0.y, b0.z, b0.w, b1.x, b1.y, b1.z, b1.w};
            bf16x8 hn;
#pragma unroll
            for (int j = 0; j < 8; ++j) {
                float x = fmaxf(fmaf(bf2f(((const u16*)&hf)[j]), av[j], bv[j]), 0.f);
                ((u16*)&hn)[j] = bf16rne(x);
            }
            c = __builtin_amdgcn_mfma_f32_16x16x32_bf16(hn, wfr[kc], c, 0, 0, 0);
        }
        // scatter xyz to per-wave LDS strip (wave-internal: DS ops are wave-ordered)
        if (i16 < 3) {
#pragma unroll
            for (int j = 0; j < 4; ++j) bp[wv][q * 4 + j][i16] = c[j];
        }
        if (lane < 16) {
            int row = rb + lane;
            float4 P = *(const float4*)bp[wv][lane];
            float bpx = P.x + b2x, bpy = P.y + b2y, bpz = P.z + b2z;
            const float* cp = coord + (size_t)row * 3;
            const float* ip = cent + (size_t)row * 3;
            float gx = ip[0] - cp[0], gy = ip[1] - cp[1], gz = ip[2] - cp[2];
            float mk = (inst[row] != -1) ? 1.f : 0.f;
            float l1 = fabsf(bpx - gx) + fabsf(bpy - gy) + fabsf(bpz - gz);
            float np = sqrtf(fmaf(bpx, bpx, fmaf(bpy, bpy, bpz * bpz)));
            float ng = sqrtf(fmaf(gx, gx, fmaf(gy, gy, gz * gz)));
            float dp = fmaf(bpx, gx, fmaf(bpy, gy, bpz * gz));
            float cosv = -dp / ((np + 1e-8f) * (ng + 1e-8f));
            l1a = fmaf(l1, mk, l1a);
            cosa = fmaf(cosv, mk, cosa);
            ma += mk;
        }
    }
#pragma unroll
    for (int d = 1; d < 64; d <<= 1) {
        l1a += __shfl_xor(l1a, d);
        cosa += __shfl_xor(cosa, d);
        ma += __shfl_xor(ma, d);
    }
    if (lane == 0) { red[wv] = l1a; red[4 + wv] = cosa; red[8 + wv] = ma; }
    __syncthreads();
    if (t == 0) {
        int slot = blockIdx.x & (LSLOT - 1);
        atomicAdd(aggL + slot * 4 + 0, red[0] + red[1] + red[2] + red[3]);
        atomicAdd(aggL + slot * 4 + 1, red[4] + red[5] + red[6] + red[7]);
        atomicAdd(aggL + slot * 4 + 2, red[8] + red[9] + red[10] + red[11]);
    }
}

// ---------------------------------------------------------------------------
// kernel 4: final scalars — reduce NLL + loss slots, emit 4 outputs (1 wave)
// ---------------------------------------------------------------------------
__global__ void k_final(const float* __restrict__ aggNLL, const float* __restrict__ aggL,
                        float* __restrict__ out) {
    int lane = threadIdx.x;   // 0..63
    float nll = 0.f, cnt = 0.f;
#pragma unroll
    for (int i = 0; i < 4; ++i) {
        int s = lane + i * 64;
        nll += aggNLL[s * 2 + 0];
        cnt += aggNLL[s * 2 + 1];
    }
    float l1 = aggL[lane * 4 + 0];
    float cs = aggL[lane * 4 + 1];
    float mk = aggL[lane * 4 + 2];
#pragma unroll
    for (int d = 1; d < 64; d <<= 1) {
        nll += __shfl_xor(nll, d);
        cnt += __shfl_xor(cnt, d);
        l1 += __shfl_xor(l1, d);
        cs += __shfl_xor(cs, d);
        mk += __shfl_xor(mk, d);
    }
    if (lane == 0) {
        float seg = nll / (cnt + 1e-8f);
        float l1l = l1 / (mk + 1e-8f);
        float csl = cs / (mk + 1e-8f);
        out[0] = seg + l1l + csl;
        out[1] = seg;
        out[2] = l1l;
        out[3] = csl;
    }
}

extern "C" void kernel_launch(void* const* d_in, const int* in_sizes, int n_in,
                              void* d_out, int out_size, void* d_ws, size_t ws_size,
                              hipStream_t stream) {
    const float* feat   = (const float*)d_in[0];
    const float* coord  = (const float*)d_in[1];
    const float* cent   = (const float*)d_in[2];
    const int* segment  = (const int*)d_in[3];
    const int* inst     = (const int*)d_in[4];
    const float* w1     = (const float*)d_in[5];
    const float* b1     = (const float*)d_in[6];
    const float* gamma  = (const float*)d_in[7];
    const float* beta   = (const float*)d_in[8];
    const float* w2     = (const float*)d_in[9];
    const float* b2     = (const float*)d_in[10];
    const float* wsm    = (const float*)d_in[11];
    const float* bs     = (const float*)d_in[12];
    float* out = (float*)d_out;

    char* wsb = (char*)d_ws;
    u16* h_ws    = (u16*)wsb;
    u16* Wt      = (u16*)(wsb + OFF_WT);
    float* aggBN = (float*)(wsb + OFF_AGGBN);
    float* aggNL = (float*)(wsb + OFF_AGGNL);
    float* aggL  = (float*)(wsb + OFF_AGGL);
    float* Aarr  = (float*)(wsb + OFF_AB);
    float* Barr  = Aarr + 256;

    if (ws_size < WS_NEED)
        fprintf(stderr, "kernel_launch: ws_size=%zu < needed %zu — WILL CORRUPT\n",
                ws_size, (size_t)WS_NEED);

    hipMemsetAsync(wsb + MEMSET_OFF, 0, MEMSET_LEN, stream);
    k_prep<<<256, 320, 0, stream>>>(w1, wsm, Wt);
    k_gemm<<<NBLK, 256, 0, stream>>>(feat, b1, bs, segment, Wt, h_ws, aggBN, aggNL);
    k_reduce<<<256, 64, 0, stream>>>(gamma, beta, aggBN, Aarr, Barr);
    k_loss<<<1024, 256, 0, stream>>>(h_ws, Aarr, Barr, w2, b2, coord, cent, inst, aggL);
    k_final<<<1, 64, 0, stream>>>(aggNL, aggL, out);
}

// Round 5
// 508.742 us; speedup vs baseline: 1.6187x; 1.4137x over previous
//
#include <hip/hip_runtime.h>
#include <cstdio>
#include <cstdint>

typedef unsigned int u32;
typedef unsigned short u16;
typedef short bf16x8 __attribute__((ext_vector_type(8)));   // 8 bf16 = 4 VGPRs (MFMA A/B operand)
typedef float f32x4 __attribute__((ext_vector_type(4)));    // MFMA C/D operand

#define NPTS 262144
#define CDIM 256
#define KCLS 20
#define NBLK 4096          // k_gemm blocks (BM=64)
#define NSLOT 256          // BN/NLL aggregation slots
#define LSLOT 256          // loss aggregation slots

// ---- workspace layout (bytes) ----
// [0, 134217728)       : h bf16 [N][256] row-major
// + 163840             : Wt bf16 [320][256]
// + 524288             : aggBN  [256][512] f32 (sum_h[256] | sumsq_h[256] per slot)
// + 2048               : aggNLL [256][2]  f32 (nll, cnt)
// + 4096               : aggL   [256][4]  f32 (l1, cos, mask, pad)
// + 2048               : Aarr[256], Barr[256]
#define OFF_WT    ((size_t)134217728)
#define OFF_AGGBN (OFF_WT + (size_t)163840)
#define OFF_AGGNL (OFF_AGGBN + (size_t)524288)
#define OFF_AGGL  (OFF_AGGNL + (size_t)2048)
#define OFF_AB    (OFF_AGGL + (size_t)4096)
#define WS_NEED   (OFF_AB + (size_t)2048)
#define MEMSET_OFF OFF_AGGBN
#define MEMSET_LEN ((size_t)(524288 + 2048 + 4096))

__device__ __forceinline__ u16 bf16rne(float x) {
    u32 u = __float_as_uint(x);
    u32 r = u + 0x7FFFu + ((u >> 16) & 1u);   // round-to-nearest-even
    return (u16)(r >> 16);
}
__device__ __forceinline__ float bf2f(u16 b) {
    return __uint_as_float(((u32)b) << 16);
}

// ---------------------------------------------------------------------------
// kernel 0: build Wt[320][256] bf16 = transposed [w1 | ws | zero-pad]
// ---------------------------------------------------------------------------
__global__ void k_prep(const float* __restrict__ w1, const float* __restrict__ wsm,
                       u16* __restrict__ Wt) {
    int k = blockIdx.x;      // 0..255
    int n = threadIdx.x;     // 0..319
    float v = 0.f;
    if (n < 256) v = w1[k * 256 + n];
    else if (n < 256 + KCLS) v = wsm[k * KCLS + (n - 256)];
    Wt[n * 256 + k] = bf16rne(v);
}

// ---------------------------------------------------------------------------
// kernel 1: h = feat @ w1 (+b1) via bf16 MFMA; fused logits = feat @ ws (+bs)
// R2 structure (coalesced LDS staging) with BK=64: 4 barrier-pairs, 36
// MFMA/wave per staged chunk. As 8 KB + Bs 40 KB = 48 KB LDS -> 3 blocks/CU.
// ---------------------------------------------------------------------------
__global__ __launch_bounds__(256) void k_gemm(
    const float* __restrict__ feat, const float* __restrict__ b1,
    const float* __restrict__ bs, const int* __restrict__ segment,
    const u16* __restrict__ Wt, u16* __restrict__ h_out,
    float* __restrict__ aggBN, float* __restrict__ aggNLL)
{
    // 49152 B: K-loop As [8 kq][64 m] + Bs [8 kq][320 n] (16B slots);
    // epilogue reuses first 33792 B as 64x(264 u16) transpose buffer.
    __shared__ uint4 smem4[3072];
    uint4* const As4 = smem4;          // 512 slots
    uint4* const Bs4 = smem4 + 512;    // 2560 slots

    const int t = threadIdx.x;
    const int lane = t & 63;
    const int wv = t >> 6;
    const int q = lane >> 4;          // k-quad within 32-subchunk / row-quad of C
    const int i16 = lane & 15;
    const int row0 = blockIdx.x * 64;
    const int slot = blockIdx.x & (NSLOT - 1);

    const f32x4 fz = {0.f, 0.f, 0.f, 0.f};
    f32x4 acc[4][4];                  // [row-tile][col-tile]
    f32x4 lacc[2];                    // logit col-tiles (cols 256+{0,16})
#pragma unroll
    for (int r = 0; r < 4; ++r)
#pragma unroll
        for (int c = 0; c < 4; ++c) acc[r][c] = fz;
    lacc[0] = fz; lacc[1] = fz;

    // feat staging: thread t -> row sm (0..63), k-lane sq (0..3); per iter it
    // covers k = {k0+sq*8..+8} and {k0+32+sq*8..+8} (16 fp32 -> 2 ds_write_b128)
    const int sm = t >> 2;
    const int sq = t & 3;
    const float* fsrc = feat + (size_t)(row0 + sm) * 256 + sq * 8;
    const int wsl = sm ^ (sq << 2);
    const int As_slot0 = sq * 64 + wsl;          // kq = sq
    const int As_slot1 = (sq + 4) * 64 + wsl;    // kq = sq+4

    float4 f0 = *(const float4*)(fsrc);
    float4 f1 = *(const float4*)(fsrc + 4);
    float4 f2 = *(const float4*)(fsrc + 32);
    float4 f3 = *(const float4*)(fsrc + 36);

#pragma unroll 1
    for (int kc = 0; kc < 4; ++kc) {
        const int k0 = kc * 64;
        // ---- stage feat (fp32 -> bf16, two ds_write_b128) ----
        {
            uint4 pk;
            pk.x = (u32)bf16rne(f0.x) | ((u32)bf16rne(f0.y) << 16);
            pk.y = (u32)bf16rne(f0.z) | ((u32)bf16rne(f0.w) << 16);
            pk.z = (u32)bf16rne(f1.x) | ((u32)bf16rne(f1.y) << 16);
            pk.w = (u32)bf16rne(f1.z) | ((u32)bf16rne(f1.w) << 16);
            As4[As_slot0] = pk;
            pk.x = (u32)bf16rne(f2.x) | ((u32)bf16rne(f2.y) << 16);
            pk.y = (u32)bf16rne(f2.z) | ((u32)bf16rne(f2.w) << 16);
            pk.z = (u32)bf16rne(f3.x) | ((u32)bf16rne(f3.y) << 16);
            pk.w = (u32)bf16rne(f3.z) | ((u32)bf16rne(f3.w) << 16);
            As4[As_slot1] = pk;
        }
        // ---- stage Wt slab (64 k-cols) via global_load_lds width=16 ----
        // wave wv: kq = wv (k0+wv*8) and kq = wv+4 (k0+32+wv*8)
#pragma unroll
        for (int i = 0; i < 5; ++i) {
            const u16* src = Wt + (size_t)(i * 64 + lane) * 256 + k0 + wv * 8;
            u32* dst0 = (u32*)&Bs4[wv * 320 + i * 64];
            __builtin_amdgcn_global_load_lds(
                (const __attribute__((address_space(1))) u32*)src,
                (__attribute__((address_space(3))) u32*)dst0, 16, 0, 0);
            u32* dst1 = (u32*)&Bs4[(wv + 4) * 320 + i * 64];
            __builtin_amdgcn_global_load_lds(
                (const __attribute__((address_space(1))) u32*)(src + 32),
                (__attribute__((address_space(3))) u32*)dst1, 16, 0, 0);
        }
        __syncthreads();

        // prefetch next feat chunk under the MFMAs
        float4 fn0, fn1, fn2, fn3;
        if (kc < 3) {
            const float* p = fsrc + (kc + 1) * 64;
            fn0 = *(const float4*)(p);
            fn1 = *(const float4*)(p + 4);
            fn2 = *(const float4*)(p + 32);
            fn3 = *(const float4*)(p + 36);
        }

        // ---- fragments + MFMA: two 32-wide subchunks ----
#pragma unroll
        for (int s = 0; s < 2; ++s) {
            const int kq = s * 4 + q;
            bf16x8 bfr[4], lbf[2], af[4], la;
#pragma unroll
            for (int c = 0; c < 4; ++c)
                bfr[c] = *(const bf16x8*)&Bs4[kq * 320 + wv * 64 + c * 16 + i16];
#pragma unroll
            for (int x = 0; x < 2; ++x)
                lbf[x] = *(const bf16x8*)&Bs4[kq * 320 + 256 + x * 16 + i16];
#pragma unroll
            for (int r = 0; r < 4; ++r)
                af[r] = *(const bf16x8*)&As4[kq * 64 + ((r * 16 + i16) ^ (q << 2))];
            la = *(const bf16x8*)&As4[kq * 64 + ((wv * 16 + i16) ^ (q << 2))];

#pragma unroll
            for (int r = 0; r < 4; ++r)
#pragma unroll
                for (int c = 0; c < 4; ++c)
                    acc[r][c] = __builtin_amdgcn_mfma_f32_16x16x32_bf16(af[r], bfr[c], acc[r][c], 0, 0, 0);
#pragma unroll
            for (int x = 0; x < 2; ++x)
                lacc[x] = __builtin_amdgcn_mfma_f32_16x16x32_bf16(la, lbf[x], lacc[x], 0, 0, 0);
        }
        __syncthreads();
        f0 = fn0; f1 = fn1; f2 = fn2; f3 = fn3;
    }

    // ---- epilogue (validated R2 version) ----
    float b1v[4];
#pragma unroll
    for (int c = 0; c < 4; ++c) b1v[c] = b1[wv * 64 + c * 16 + i16];
    float bsv0 = bs[i16];
    float bsv1 = (16 + i16 < KCLS) ? bs[16 + i16] : 0.f;

    // seg-head NLL for this wave's 16 logit rows. C layout: col=i16, row=q*4+j.
    float nllacc = 0.f, cntacc = 0.f;
#pragma unroll
    for (int j = 0; j < 4; ++j) {
        int rowr = row0 + wv * 16 + q * 4 + j;
        float l0 = lacc[0][j] + bsv0;                       // cols 0..15
        float l1raw = lacc[1][j] + bsv1;                    // cols 16..31 (only 16..19 real)
        float l1m = (i16 < 4) ? l1raw : -3.0e38f;
        float mx = fmaxf(l0, l1m);
#pragma unroll
        for (int d = 1; d < 16; d <<= 1) mx = fmaxf(mx, __shfl_xor(mx, d));
        float s = __expf(l0 - mx) + ((i16 < 4) ? __expf(l1raw - mx) : 0.f);
#pragma unroll
        for (int d = 1; d < 16; d <<= 1) s += __shfl_xor(s, d);
        int tg = segment[rowr];
        float v0 = __shfl(l0, (lane & 48) + (tg & 15));
        float v1 = __shfl(l1raw, (lane & 48) + ((tg - 16) & 15));
        float lt = (tg < 16) ? v0 : v1;
        if (i16 == 0 && tg >= 0) {                          // ignore_index = -1
            nllacc += __logf(s) + mx - lt;
            cntacc += 1.f;
        }
    }
#pragma unroll
    for (int d = 1; d < 64; d <<= 1) {
        nllacc += __shfl_xor(nllacc, d);
        cntacc += __shfl_xor(cntacc, d);
    }
    if (lane == 0) {
        atomicAdd(aggNLL + slot * 2 + 0, nllacc);
        atomicAdd(aggNLL + slot * 2 + 1, cntacc);
    }

    // per-channel sum / sumsq over this block's 64 rows -> 256-slot fan-out
#pragma unroll
    for (int c = 0; c < 4; ++c) {
        float s1 = 0.f, s2 = 0.f;
#pragma unroll
        for (int r = 0; r < 4; ++r)
#pragma unroll
            for (int j = 0; j < 4; ++j) {
                float v = acc[r][c][j] + b1v[c];
                s1 += v; s2 = fmaf(v, v, s2);
            }
        s1 += __shfl_xor(s1, 16); s1 += __shfl_xor(s1, 32);
        s2 += __shfl_xor(s2, 16); s2 += __shfl_xor(s2, 32);
        if (q == 0) {
            int ch = wv * 64 + c * 16 + i16;
            atomicAdd(aggBN + slot * 512 + ch, s1);
            atomicAdd(aggBN + slot * 512 + 256 + ch, s2);
        }
    }

    // transpose h to row-major via LDS (rows padded to 264 u16 = 528 B)
    u16* Ht = (u16*)smem4;
#pragma unroll
    for (int r = 0; r < 4; ++r)
#pragma unroll
        for (int c = 0; c < 4; ++c)
#pragma unroll
            for (int j = 0; j < 4; ++j) {
                float v = acc[r][c][j] + b1v[c];
                int rw = r * 16 + q * 4 + j;
                int cl = wv * 64 + c * 16 + i16;
                Ht[rw * 264 + cl] = bf16rne(v);
            }
    __syncthreads();
    // coalesced store: 64 rows x 512 B
#pragma unroll
    for (int i = 0; i < 8; ++i) {
        int chunk = i * 256 + t;          // 0..2047 of 16B
        int m = chunk >> 5;
        int off = (chunk & 31) * 16;
        uint4 v = *(const uint4*)((const char*)smem4 + m * 528 + off);
        *(uint4*)((char*)h_out + (size_t)(row0 + m) * 512 + off) = v;
    }
}

// ---------------------------------------------------------------------------
// kernel 2: reduce BN slot partials -> affine hn = h*A + B  (256 blocks x 64)
// ---------------------------------------------------------------------------
__global__ void k_reduce(const float* __restrict__ gamma, const float* __restrict__ beta,
                         const float* __restrict__ aggBN,
                         float* __restrict__ Aarr, float* __restrict__ Barr) {
    int c = blockIdx.x;      // channel
    int l = threadIdx.x;     // 0..63
    float s1 = 0.f, s2 = 0.f;
#pragma unroll
    for (int i = 0; i < 4; ++i) {
        int s = l + i * 64;
        s1 += aggBN[s * 512 + c];
        s2 += aggBN[s * 512 + 256 + c];
    }
#pragma unroll
    for (int d = 1; d < 64; d <<= 1) {
        s1 += __shfl_xor(s1, d);
        s2 += __shfl_xor(s2, d);
    }
    if (l == 0) {
        const float inv = 1.f / (float)NPTS;
        float mu = s1 * inv;
        float var = fmaxf(s2 * inv - mu * mu, 0.f);   // biased var (torch BN)
        float a = gamma[c] * rsqrtf(var + 1e-3f);
        Aarr[c] = a;
        Barr[c] = beta[c] - mu * a;
    }
}

// ---------------------------------------------------------------------------
// kernel 3: bias_pred = relu(h*A+B) @ w2 + b2 via MFMA, masked L1 + cosine.
// COALESCED: block stages a 64x256 bf16 h-tile into LDS (8 linear dwordx4
// loads/thread), fragments read from LDS. One barrier per block.
// ---------------------------------------------------------------------------
__global__ __launch_bounds__(256) void k_loss(
    const u16* __restrict__ h, const float* __restrict__ Aarr, const float* __restrict__ Barr,
    const float* __restrict__ w2, const float* __restrict__ b2,
    const float* __restrict__ coord, const float* __restrict__ cent,
    const int* __restrict__ inst, float* __restrict__ aggL)
{
    __shared__ u16 hs[64 * 264];      // 33792 B, 528 B row stride
    __shared__ float w2s[768];
    __shared__ float As_l[256], Bs_l[256];
    __shared__ float bp[4][16][4];    // per wave: 16 rows x {x,y,z,pad}
    __shared__ float red[12];

    const int t = threadIdx.x;
    const int lane = t & 63;
    const int wv = t >> 6;
    const int q = lane >> 4;
    const int i16 = lane & 15;
    const int row0 = blockIdx.x * 64;

    // coalesced stage of h tile (64 rows x 512 B)
#pragma unroll
    for (int i = 0; i < 8; ++i) {
        int chunk = i * 256 + t;          // 0..2047 of 16B
        int m = chunk >> 5;
        int off = (chunk & 31) * 16;
        *(uint4*)((char*)hs + m * 528 + off) =
            *(const uint4*)((const char*)h + (size_t)(row0 + m) * 512 + off);
    }
    if (t < 256) { As_l[t] = Aarr[t]; Bs_l[t] = Barr[t]; }
    for (int i = t; i < 768; i += 256) w2s[i] = w2[i];
    __syncthreads();

    // w2 B-frags for all 8 k-chunks (n=i16, only n<3 nonzero)
    bf16x8 wfr[8];
#pragma unroll
    for (int kc = 0; kc < 8; ++kc) {
        bf16x8 f;
#pragma unroll
        for (int j = 0; j < 8; ++j) {
            int k = kc * 32 + q * 8 + j;
            float v = (i16 < 3) ? w2s[k * 3 + i16] : 0.f;
            ((u16*)&f)[j] = bf16rne(v);
        }
        wfr[kc] = f;
    }
    float b2x = b2[0], b2y = b2[1], b2z = b2[2];

    // wave wv handles rows [row0+wv*16, +16): A-frag m=i16, k=q*8+j
    const f32x4 fz = {0.f, 0.f, 0.f, 0.f};
    f32x4 c = fz;
#pragma unroll
    for (int kc = 0; kc < 8; ++kc) {
        bf16x8 hf = *(const bf16x8*)(hs + (wv * 16 + i16) * 264 + kc * 32 + q * 8);
        float4 a0 = *(const float4*)(As_l + kc * 32 + q * 8);
        float4 a1 = *(const float4*)(As_l + kc * 32 + q * 8 + 4);
        float4 b0 = *(const float4*)(Bs_l + kc * 32 + q * 8);
        float4 b1 = *(const float4*)(Bs_l + kc * 32 + q * 8 + 4);
        float av[8] = {a0.x, a0.y, a0.z, a0.w, a1.x, a1.y, a1.z, a1.w};
        float bv[8] = {b0.x, b0.y, b0.z, b0.w, b1.x, b1.y, b1.z, b1.w};
        bf16x8 hn;
#pragma unroll
        for (int j = 0; j < 8; ++j) {
            float x = fmaxf(fmaf(bf2f(((const u16*)&hf)[j]), av[j], bv[j]), 0.f);
            ((u16*)&hn)[j] = bf16rne(x);
        }
        c = __builtin_amdgcn_mfma_f32_16x16x32_bf16(hn, wfr[kc], c, 0, 0, 0);
    }

    // scatter xyz to per-wave LDS strip (wave-internal: DS ops are wave-ordered)
    if (i16 < 3) {
#pragma unroll
        for (int j = 0; j < 4; ++j) bp[wv][q * 4 + j][i16] = c[j];
    }
    float l1a = 0.f, cosa = 0.f, ma = 0.f;
    if (lane < 16) {
        int row = row0 + wv * 16 + lane;
        float4 P = *(const float4*)bp[wv][lane];
        float bpx = P.x + b2x, bpy = P.y + b2y, bpz = P.z + b2z;
        const float* cp = coord + (size_t)row * 3;
        const float* ip = cent + (size_t)row * 3;
        float gx = ip[0] - cp[0], gy = ip[1] - cp[1], gz = ip[2] - cp[2];
        float mk = (inst[row] != -1) ? 1.f : 0.f;
        float l1 = fabsf(bpx - gx) + fabsf(bpy - gy) + fabsf(bpz - gz);
        float np = sqrtf(fmaf(bpx, bpx, fmaf(bpy, bpy, bpz * bpz)));
        float ng = sqrtf(fmaf(gx, gx, fmaf(gy, gy, gz * gz)));
        float dp = fmaf(bpx, gx, fmaf(bpy, gy, bpz * gz));
        float cosv = -dp / ((np + 1e-8f) * (ng + 1e-8f));
        l1a = l1 * mk;
        cosa = cosv * mk;
        ma = mk;
    }
#pragma unroll
    for (int d = 1; d < 64; d <<= 1) {
        l1a += __shfl_xor(l1a, d);
        cosa += __shfl_xor(cosa, d);
        ma += __shfl_xor(ma, d);
    }
    if (lane == 0) { red[wv] = l1a; red[4 + wv] = cosa; red[8 + wv] = ma; }
    __syncthreads();
    if (t == 0) {
        int slot = blockIdx.x & (LSLOT - 1);
        atomicAdd(aggL + slot * 4 + 0, red[0] + red[1] + red[2] + red[3]);
        atomicAdd(aggL + slot * 4 + 1, red[4] + red[5] + red[6] + red[7]);
        atomicAdd(aggL + slot * 4 + 2, red[8] + red[9] + red[10] + red[11]);
    }
}

// ---------------------------------------------------------------------------
// kernel 4: final scalars — reduce NLL + loss slots, emit 4 outputs (1 wave)
// ---------------------------------------------------------------------------
__global__ void k_final(const float* __restrict__ aggNLL, const float* __restrict__ aggL,
                        float* __restrict__ out) {
    int lane = threadIdx.x;   // 0..63
    float nll = 0.f, cnt = 0.f, l1 = 0.f, cs = 0.f, mk = 0.f;
#pragma unroll
    for (int i = 0; i < 4; ++i) {
        int s = lane + i * 64;
        nll += aggNLL[s * 2 + 0];
        cnt += aggNLL[s * 2 + 1];
        l1 += aggL[s * 4 + 0];
        cs += aggL[s * 4 + 1];
        mk += aggL[s * 4 + 2];
    }
#pragma unroll
    for (int d = 1; d < 64; d <<= 1) {
        nll += __shfl_xor(nll, d);
        cnt += __shfl_xor(cnt, d);
        l1 += __shfl_xor(l1, d);
        cs += __shfl_xor(cs, d);
        mk += __shfl_xor(mk, d);
    }
    if (lane == 0) {
        float seg = nll / (cnt + 1e-8f);
        float l1l = l1 / (mk + 1e-8f);
        float csl = cs / (mk + 1e-8f);
        out[0] = seg + l1l + csl;
        out[1] = seg;
        out[2] = l1l;
        out[3] = csl;
    }
}

extern "C" void kernel_launch(void* const* d_in, const int* in_sizes, int n_in,
                              void* d_out, int out_size, void* d_ws, size_t ws_size,
                              hipStream_t stream) {
    const float* feat   = (const float*)d_in[0];
    const float* coord  = (const float*)d_in[1];
    const float* cent   = (const float*)d_in[2];
    const int* segment  = (const int*)d_in[3];
    const int* inst     = (const int*)d_in[4];
    const float* w1     = (const float*)d_in[5];
    const float* b1     = (const float*)d_in[6];
    const float* gamma  = (const float*)d_in[7];
    const float* beta   = (const float*)d_in[8];
    const float* w2     = (const float*)d_in[9];
    const float* b2     = (const float*)d_in[10];
    const float* wsm    = (const float*)d_in[11];
    const float* bs     = (const float*)d_in[12];
    float* out = (float*)d_out;

    char* wsb = (char*)d_ws;
    u16* h_ws    = (u16*)wsb;
    u16* Wt      = (u16*)(wsb + OFF_WT);
    float* aggBN = (float*)(wsb + OFF_AGGBN);
    float* aggNL = (float*)(wsb + OFF_AGGNL);
    float* aggL  = (float*)(wsb + OFF_AGGL);
    float* Aarr  = (float*)(wsb + OFF_AB);
    float* Barr  = Aarr + 256;

    if (ws_size < WS_NEED)
        fprintf(stderr, "kernel_launch: ws_size=%zu < needed %zu — WILL CORRUPT\n",
                ws_size, (size_t)WS_NEED);

    hipMemsetAsync(wsb + MEMSET_OFF, 0, MEMSET_LEN, stream);
    k_prep<<<256, 320, 0, stream>>>(w1, wsm, Wt);
    k_gemm<<<NBLK, 256, 0, stream>>>(feat, b1, bs, segment, Wt, h_ws, aggBN, aggNL);
    k_reduce<<<256, 64, 0, stream>>>(gamma, beta, aggBN, Aarr, Barr);
    k_loss<<<4096, 256, 0, stream>>>(h_ws, Aarr, Barr, w2, b2, coord, cent, inst, aggL);
    k_final<<<1, 64, 0, stream>>>(aggNL, aggL, out);
}